// Round 3
// baseline (3039.573 us; speedup 1.0000x reference)
//
#include <hip/hip_runtime.h>
#include <hip/hip_bf16.h>

typedef unsigned short u16;
typedef unsigned char uchar;
typedef unsigned long long u64;
typedef float f32x4 __attribute__((ext_vector_type(4)));
typedef u64 u64x2 __attribute__((ext_vector_type(2)));

#define FDIM 2048
#define NBLK 256
#define NSTEP 63
#define FLAGSTR 32   // u32 stride between block flags = 128B

__device__ __forceinline__ u16 f2b(float x) {
    __hip_bfloat16 h = __float2bfloat16(x);
    return __builtin_bit_cast(u16, h);
}
__device__ __forceinline__ float b2f(u16 u) {
    __hip_bfloat16 h = __builtin_bit_cast(__hip_bfloat16, u);
    return __bfloat162float(h);
}
__device__ __forceinline__ float sigm(float x) { return 1.0f / (1.0f + __expf(-x)); }
__device__ __forceinline__ float tanh_f(float x) { return 1.0f - 2.0f / (__expf(2.0f * x) + 1.0f); }

// manual OCP e4m3 encode (RNE), saturate to 448. No NaN inputs expected.
__device__ __forceinline__ unsigned f2fp8(float x) {
    unsigned u = __builtin_bit_cast(unsigned, x);
    unsigned s = (u >> 24) & 0x80u;
    unsigned mag = u & 0x7fffffffu;
    if (mag >= 0x43E80000u) return s | 0x7Eu;          // >= 464 -> sat 448
    int e = (int)(mag >> 23) - 127;
    if (e >= -6) {
        unsigned m = mag + 0x7FFFFu + ((mag >> 20) & 1u);   // RNE into 3 mantissa bits
        unsigned e8 = (m >> 23) - 127 + 7;
        unsigned m3 = (m >> 20) & 7u;
        if (e8 >= 16u) return s | 0x7Eu;
        return s | (e8 << 3) | m3;
    }
    float ax = __builtin_bit_cast(float, mag);
    int d = (int)__builtin_rintf(ax * 512.0f);          // subnormal grid 2^-9
    return s | (unsigned)d;
}

__device__ __forceinline__ f32x4 mfma8(long long a, long long b, f32x4 c) {
    return __builtin_amdgcn_mfma_f32_16x16x32_fp8_fp8(a, b, c, 0, 0, 0);
}

// ---------------- weight pack: fp32 -> fp8 e4m3 (x32) in per-wave MFMA stream order ----------------
__global__ __launch_bounds__(256) void k_pack(const float* __restrict__ W0, const float* __restrict__ W1,
                                              const float* __restrict__ W2, const float* __restrict__ W3,
                                              uchar* __restrict__ Wp) {
    __shared__ float lw[32][257];
    int idx = blockIdx.x;                 // [0, 8192)
    int q = idx & 3, khh = (idx >> 2) & 1, bl = (idx >> 3) & 255, cm = idx >> 11;
    const float* src = cm == 0 ? W0 : cm == 1 ? W1 : cm == 2 ? W2 : W3;
    int tid = threadIdx.x;
    int kbase = khh * 1024 + q * 256;
    for (int i = tid; i < 32 * 256; i += 256) {
        int r = i >> 8, c = i & 255;
        int gate = r >> 3, fe = r & 7;
        lw[r][c] = src[((size_t)(gate * 2048 + bl * 8 + fe)) * 2048 + kbase + c];
    }
    __syncthreads();
#pragma unroll
    for (int it = 0; it < 2; ++it) {
        int u = it * 256 + tid;           // [0,512)
        int gp = u >> 8, kk2i = (u >> 6) & 3, lane = u & 63;
        int kk2 = q * 4 + kk2i;
        unsigned wrd[4];
#pragma unroll
        for (int wi = 0; wi < 4; ++wi) {
            unsigned acc = 0;
#pragma unroll
            for (int byi = 0; byi < 4; ++byi) {
                int i2 = wi * 4 + byi;
                int kk = 2 * kk2 + (i2 >> 3), e = i2 & 7;
                int r = (2 * gp + ((lane & 15) >> 3)) * 8 + (lane & 7);
                int kl = kk * 32 + ((lane >> 4) << 3) + e - q * 256;
                acc |= f2fp8(lw[r][kl] * 32.0f) << (byi * 8);
            }
            wrd[wi] = acc;
        }
        size_t off = ((((size_t)cm * 256 + bl) * 2 + gp) * 2 + khh) * 16384 + (size_t)kk2 * 1024 + (size_t)lane * 16;
        *(uint4*)(Wp + off) = make_uint4(wrd[0], wrd[1], wrd[2], wrd[3]);
    }
}

__global__ void k_bias(const float* __restrict__ bi0, const float* __restrict__ bh0,
                       const float* __restrict__ bi1, const float* __restrict__ bh1,
                       float* __restrict__ bias0, float* __restrict__ bias1) {
    int i = blockIdx.x * blockDim.x + threadIdx.x;
    if (i < 4 * FDIM) {
        bias0[i] = bi0[i] + bh0[i];
        bias1[i] = bi1[i] + bh1[i];
    }
}

// ---------------- input 1x1 conv -> seq layout [t][b][2048] fp8 (x4) ----------------
__global__ __launch_bounds__(256) void k_seqprep(const float* __restrict__ x,
                                                 const float* __restrict__ w_in,
                                                 const float* __restrict__ b_in,
                                                 uchar* __restrict__ seqb) {
    int h = blockIdx.x >> 4, b = blockIdx.x & 15;
    __shared__ float xs[256][32];
    __shared__ float wl[64][257];
    int tid = threadIdx.x;
    for (int i = tid; i < 256 * 32; i += 256) {
        int c = i >> 5, w = i & 31;
        xs[c][w] = x[(((size_t)b * 256 + c) * 32 + h) * 32 + w];
    }
    for (int i = tid; i < 64 * 256; i += 256) {
        int cb = i >> 8, c = i & 255;
        wl[cb][c] = w_in[i];
    }
    __syncthreads();
    int w = (tid * 8) >> 6, cb0 = (tid * 8) & 63;
    float acc[8];
#pragma unroll
    for (int j = 0; j < 8; ++j) acc[j] = b_in[cb0 + j];
    for (int c = 0; c < 256; ++c) {
        float xv = xs[c][w];
#pragma unroll
        for (int j = 0; j < 8; ++j) acc[j] += xv * wl[cb0 + j][c];
    }
    unsigned lo = 0, hi2 = 0;
#pragma unroll
    for (int j = 0; j < 4; ++j) lo |= f2fp8(acc[j] * 4.0f) << (j * 8);
#pragma unroll
    for (int j = 0; j < 4; ++j) hi2 |= f2fp8(acc[4 + j] * 4.0f) << (j * 8);
    *(uint2*)(seqb + ((size_t)h * 16 + b) * FDIM + tid * 8) = make_uint2(lo, hi2);
}

// stage both A-operands (fp8 [b][2048]) into granule-transposed swizzled LDS.
__device__ __forceinline__ void stageA(char* At, const uchar* __restrict__ xop, const uchar* __restrict__ hop) {
    int tid = threadIdx.x;
#pragma unroll
    for (int it = 0; it < 8; ++it) {
        int u = it * 512 + tid;              // [0,4096)
        int op = u >> 11;
        int uu = u & 2047;
        int b = uu >> 7, gp2 = uu & 127;
        const uchar* s = (op ? hop : xop) + b * 2048 + gp2 * 16;
        uint4 v = *(const uint4*)s;
        int slot = gp2 * 16 + (b ^ (gp2 & 15));
        *(uint4*)(At + (size_t)op * 32768 + (size_t)slot * 16) = v;
    }
}

// one LSTM cell; ends with flag-array grid barrier, prefetching next cell's
// weight fragments (static data) into wf[] between flag store and poll.
__device__ __forceinline__ void do_cell(char* At, float (*gbuf)[16][16],
                                        u64x2 (&wf)[16], const uchar* __restrict__ nxtw,
                                        const uchar* __restrict__ xop, const uchar* __restrict__ hop,
                                        uchar* __restrict__ hdst, u16* __restrict__ odst,
                                        const float* bia, float& cst,
                                        unsigned* __restrict__ flags, unsigned target, int col, int bl) {
    int tid = threadIdx.x, lane = tid & 63, w = tid >> 6;
    int m = (w >> 1) & 1;
    stageA(At, xop, hop);
    __syncthreads();

    f32x4 acc0 = {0.f, 0.f, 0.f, 0.f}, acc1 = {0.f, 0.f, 0.f, 0.f};
    const char* ab = At + m * 32768;
    int b16 = lane & 15, hi = lane >> 4;
    int loff = (hi & 1) * 8;
#pragma unroll
    for (int kk2 = 0; kk2 < 16; ++kk2) {
        int P0 = 4 * kk2 + (hi >> 1), P1 = P0 + 2;
        long long a0 = *(const long long*)(ab + (P0 * 16 + (b16 ^ (P0 & 15))) * 16 + loff);
        acc0 = mfma8(a0, (long long)wf[kk2].x, acc0);
        long long a1 = *(const long long*)(ab + (P1 * 16 + (b16 ^ (P1 & 15))) * 16 + loff);
        acc1 = mfma8(a1, (long long)wf[kk2].y, acc1);
    }
    f32x4 acc = acc0 + acc1;
    int brow = hi * 4;
#pragma unroll
    for (int i = 0; i < 4; ++i) gbuf[w][brow + i][b16] = acc[i];
    __syncthreads();

    if (tid < 128) {
        int b = tid >> 3, f = tid & 7;
        float gv[4];
#pragma unroll
        for (int g = 0; g < 4; ++g) {
            int gpp = g >> 1, jl = ((g & 1) << 3) | f;
            float s = 0.f;
#pragma unroll
            for (int mk = 0; mk < 4; ++mk)
                s += gbuf[gpp + ((mk & 1) << 1) + ((mk >> 1) << 2)][b][jl];
            gv[g] = s * (1.0f / 128.0f) + bia[g];
        }
        float cn = sigm(gv[1]) * cst + sigm(gv[0]) * tanh_f(gv[2]);
        float hn = sigm(gv[3]) * tanh_f(cn);
        cst = cn;
        hdst[(size_t)b * FDIM + col] = (uchar)f2fp8(hn * 4.0f);
        if (odst) odst[(size_t)b * FDIM + col] = f2b(hn);
    }

    // ---- grid barrier (flag array, 128B-padded; prefetch overlapped) ----
    __syncthreads();                       // all h-writes drained to L2 per-wave
    if (tid == 0) {
        __builtin_amdgcn_fence(__ATOMIC_RELEASE, "agent");   // flush L2 -> L3
        __hip_atomic_store(flags + (size_t)bl * FLAGSTR, target,
                           __ATOMIC_RELAXED, __HIP_MEMORY_SCOPE_AGENT);
    }
    {   // prefetch next cell's weight fragments; latency hides under the poll
        const u64x2* np = (const u64x2*)nxtw;
#pragma unroll
        for (int i = 0; i < 16; ++i) wf[i] = np[(size_t)i * 64];
    }
    if (tid < NBLK) {
        while (__hip_atomic_load(flags + (size_t)tid * FLAGSTR,
                                 __ATOMIC_RELAXED, __HIP_MEMORY_SCOPE_AGENT) < target)
            __builtin_amdgcn_s_sleep(1);
    }
    __syncthreads();
    __builtin_amdgcn_fence(__ATOMIC_ACQUIRE, "agent");       // invalidate L1/L2
}

__global__ __launch_bounds__(512, 2) void k_lstm(const uchar* __restrict__ Wp,
                                                 const float* __restrict__ bias0,
                                                 const float* __restrict__ bias1,
                                                 const uchar* __restrict__ seqb,
                                                 uchar* __restrict__ h0, uchar* __restrict__ h1,
                                                 u16* __restrict__ seqout, unsigned* __restrict__ flags) {
    __shared__ char At[65536];
    __shared__ float gbuf[8][16][16];
    int tid = threadIdx.x, lane = tid & 63, w = tid >> 6;
    int gp = w & 1, m = (w >> 1) & 1, kh = w >> 2;
    int bl = blockIdx.x;
    size_t so0 = ((((size_t)(0 + m) * 256 + bl) * 2 + gp) * 2 + kh) * 16384 + (size_t)lane * 16;
    size_t so1 = ((((size_t)(2 + m) * 256 + bl) * 2 + gp) * 2 + kh) * 16384 + (size_t)lane * 16;
    const uchar* wp0 = Wp + so0;
    const uchar* wp1 = Wp + so1;
    int f = tid & 7, col = bl * 8 + f;
    float c0 = 0.f, c1 = 0.f;
    float bia[8];
    if (tid < 128) {
#pragma unroll
        for (int g = 0; g < 4; ++g) {
            bia[g] = bias0[g * FDIM + col];
            bia[4 + g] = bias1[g * FDIM + col];
        }
    }
    // prologue: load first cell's weight fragments
    u64x2 wf[16];
    {
        const u64x2* np = (const u64x2*)wp0;
#pragma unroll
        for (int i = 0; i < 16; ++i) wf[i] = np[(size_t)i * 64];
    }
    const size_t BF = (size_t)16 * FDIM;
    unsigned target = 0;
    for (int st = 0; st < NSTEP; ++st) {
        int cur = st & 1, prv = cur ^ 1;
        const uchar* x0 = (st < 32) ? (seqb + (size_t)st * BF) : (h1 + (size_t)prv * BF);
        target += 1;
        do_cell(At, gbuf, wf, wp1, x0, h0 + (size_t)prv * BF,
                h0 + (size_t)cur * BF, nullptr, bia, c0, flags, target, col, bl);
        u16* od = (st >= 31) ? (seqout + (size_t)(st - 31) * BF) : nullptr;
        target += 1;
        do_cell(At, gbuf, wf, wp0, h0 + (size_t)cur * BF, h1 + (size_t)prv * BF,
                h1 + (size_t)cur * BF, od, bia + 4, c1, flags, target, col, bl);
    }
}

// ---------------- copy x into top half of output ----------------
__global__ void k_copyx(const float* __restrict__ x, float* __restrict__ out) {
    size_t n = (size_t)4096 * 256;
    size_t stride = (size_t)gridDim.x * blockDim.x;
    for (size_t i = (size_t)blockIdx.x * blockDim.x + threadIdx.x; i < n; i += stride) {
        size_t bc = i >> 8, r = i & 255;
        ((float4*)out)[bc * 512 + r] = ((const float4*)x)[i];
    }
}

// ---------------- output 1x1 conv into bottom half ----------------
__global__ __launch_bounds__(256) void k_convout(const u16* __restrict__ seqout,
                                                 const float* __restrict__ w_out,
                                                 const float* __restrict__ b_out,
                                                 float* __restrict__ out) {
    int s = blockIdx.x >> 4, b = blockIdx.x & 15;
    __shared__ float srow[2048];
    int tid = threadIdx.x;
    for (int i = tid; i < 2048; i += 256) srow[i] = b2f(seqout[((size_t)s * 16 + b) * FDIM + i]);
    __syncthreads();
    int o = tid;
    float bo = b_out[o];
    float wreg[64];
#pragma unroll
    for (int cb = 0; cb < 64; ++cb) wreg[cb] = w_out[o * 64 + cb];
    for (int w4 = 0; w4 < 8; ++w4) {
        float ac0 = bo, ac1 = bo, ac2 = bo, ac3 = bo;
#pragma unroll
        for (int cb = 0; cb < 64; ++cb) {
            float wv = wreg[cb];
            ac0 += srow[(w4 * 4 + 0) * 64 + cb] * wv;
            ac1 += srow[(w4 * 4 + 1) * 64 + cb] * wv;
            ac2 += srow[(w4 * 4 + 2) * 64 + cb] * wv;
            ac3 += srow[(w4 * 4 + 3) * 64 + cb] * wv;
        }
        float4 v; v.x = ac0; v.y = ac1; v.z = ac2; v.w = ac3;
        *(float4*)&out[(((size_t)b * 256 + o) * 64 + 32 + s) * 32 + w4 * 4] = v;
    }
}

extern "C" void kernel_launch(void* const* d_in, const int* in_sizes, int n_in,
                              void* d_out, int out_size, void* d_ws, size_t ws_size,
                              hipStream_t stream) {
    const float* x    = (const float*)d_in[0];
    const float* w_in = (const float*)d_in[1];
    const float* b_in = (const float*)d_in[2];
    const float* Wih0 = (const float*)d_in[3];
    const float* Whh0 = (const float*)d_in[4];
    const float* bih0 = (const float*)d_in[5];
    const float* bhh0 = (const float*)d_in[6];
    const float* Wih1 = (const float*)d_in[7];
    const float* Whh1 = (const float*)d_in[8];
    const float* bih1 = (const float*)d_in[9];
    const float* bhh1 = (const float*)d_in[10];
    const float* wout = (const float*)d_in[11];
    const float* bout = (const float*)d_in[12];
    float* out = (float*)d_out;
    char* ws = (char*)d_ws;

    uchar* Wp = (uchar*)ws;
    size_t off = (size_t)64 * 1024 * 1024;               // fp8 packed weights
    float* bias0 = (float*)(ws + off); off += 4 * FDIM * 4;
    float* bias1 = (float*)(ws + off); off += 4 * FDIM * 4;
    uchar* seqb = (uchar*)(ws + off); off += (size_t)32 * 16 * FDIM;
    u16* seqout = (u16*)(ws + off); off += (size_t)32 * 16 * FDIM * 2;
    size_t zoff = off;
    uchar* h0 = (uchar*)(ws + off); off += (size_t)2 * 16 * FDIM;
    uchar* h1 = (uchar*)(ws + off); off += (size_t)2 * 16 * FDIM;
    off = (off + 127) & ~(size_t)127;
    unsigned* flags = (unsigned*)(ws + off); off += (size_t)NBLK * FLAGSTR * 4;

    hipMemsetAsync(ws + zoff, 0, off - zoff, stream);

    k_pack<<<8192, 256, 0, stream>>>(Wih0, Whh0, Wih1, Whh1, Wp);
    k_bias<<<32, 256, 0, stream>>>(bih0, bhh0, bih1, bhh1, bias0, bias1);
    k_seqprep<<<512, 256, 0, stream>>>(x, w_in, b_in, seqb);
    k_lstm<<<NBLK, 512, 0, stream>>>(Wp, bias0, bias1, seqb, h0, h1, seqout, flags);
    k_copyx<<<2048, 256, 0, stream>>>(x, out);
    k_convout<<<512, 256, 0, stream>>>(seqout, wout, bout, out);
}

// Round 4
// 746.666 us; speedup vs baseline: 4.0709x; 4.0709x over previous
//
#include <hip/hip_runtime.h>
#include <hip/hip_bf16.h>

typedef unsigned short u16;
typedef unsigned char uchar;
typedef unsigned long long u64;
typedef float f32x4 __attribute__((ext_vector_type(4)));
typedef u64 u64x2 __attribute__((ext_vector_type(2)));

#define FDIM 2048
#define NBLK 256
#define NSTEP 63

__device__ __forceinline__ u16 f2b(float x) {
    __hip_bfloat16 h = __float2bfloat16(x);
    return __builtin_bit_cast(u16, h);
}
__device__ __forceinline__ float b2f(u16 u) {
    __hip_bfloat16 h = __builtin_bit_cast(__hip_bfloat16, u);
    return __bfloat162float(h);
}
__device__ __forceinline__ float sigm(float x) { return 1.0f / (1.0f + __expf(-x)); }
__device__ __forceinline__ float tanh_f(float x) { return 1.0f - 2.0f / (__expf(2.0f * x) + 1.0f); }

// manual OCP e4m3 encode (RNE), saturate to 448.
__device__ __forceinline__ unsigned f2fp8(float x) {
    unsigned u = __builtin_bit_cast(unsigned, x);
    unsigned s = (u >> 24) & 0x80u;
    unsigned mag = u & 0x7fffffffu;
    if (mag >= 0x43E80000u) return s | 0x7Eu;
    int e = (int)(mag >> 23) - 127;
    if (e >= -6) {
        unsigned m = mag + 0x7FFFFu + ((mag >> 20) & 1u);
        unsigned e8 = (m >> 23) - 127 + 7;
        unsigned m3 = (m >> 20) & 7u;
        if (e8 >= 16u) return s | 0x7Eu;
        return s | (e8 << 3) | m3;
    }
    float ax = __builtin_bit_cast(float, mag);
    int d = (int)__builtin_rintf(ax * 512.0f);
    return s | (unsigned)d;
}

__device__ __forceinline__ f32x4 mfma8(long long a, long long b, f32x4 c) {
    return __builtin_amdgcn_mfma_f32_16x16x32_fp8_fp8(a, b, c, 0, 0, 0);
}

// ---------------- weight pack: fp32 -> fp8 e4m3 (x32) in per-wave MFMA stream order ----------------
__global__ __launch_bounds__(256) void k_pack(const float* __restrict__ W0, const float* __restrict__ W1,
                                              const float* __restrict__ W2, const float* __restrict__ W3,
                                              uchar* __restrict__ Wp) {
    __shared__ float lw[32][257];
    int idx = blockIdx.x;                 // [0, 8192)
    int q = idx & 3, khh = (idx >> 2) & 1, bl = (idx >> 3) & 255, cm = idx >> 11;
    const float* src = cm == 0 ? W0 : cm == 1 ? W1 : cm == 2 ? W2 : W3;
    int tid = threadIdx.x;
    int kbase = khh * 1024 + q * 256;
    for (int i = tid; i < 32 * 256; i += 256) {
        int r = i >> 8, c = i & 255;
        int gate = r >> 3, fe = r & 7;
        lw[r][c] = src[((size_t)(gate * 2048 + bl * 8 + fe)) * 2048 + kbase + c];
    }
    __syncthreads();
#pragma unroll
    for (int it = 0; it < 2; ++it) {
        int u = it * 256 + tid;           // [0,512)
        int gp = u >> 8, kk2i = (u >> 6) & 3, lane = u & 63;
        int kk2 = q * 4 + kk2i;
        unsigned wrd[4];
#pragma unroll
        for (int wi = 0; wi < 4; ++wi) {
            unsigned acc = 0;
#pragma unroll
            for (int byi = 0; byi < 4; ++byi) {
                int i2 = wi * 4 + byi;
                int kk = 2 * kk2 + (i2 >> 3), e = i2 & 7;
                int r = (2 * gp + ((lane & 15) >> 3)) * 8 + (lane & 7);
                int kl = kk * 32 + ((lane >> 4) << 3) + e - q * 256;
                acc |= f2fp8(lw[r][kl] * 32.0f) << (byi * 8);
            }
            wrd[wi] = acc;
        }
        size_t off = ((((size_t)cm * 256 + bl) * 2 + gp) * 2 + khh) * 16384 + (size_t)kk2 * 1024 + (size_t)lane * 16;
        *(uint4*)(Wp + off) = make_uint4(wrd[0], wrd[1], wrd[2], wrd[3]);
    }
}

__global__ void k_bias(const float* __restrict__ bi0, const float* __restrict__ bh0,
                       const float* __restrict__ bi1, const float* __restrict__ bh1,
                       float* __restrict__ bias0, float* __restrict__ bias1) {
    int i = blockIdx.x * blockDim.x + threadIdx.x;
    if (i < 4 * FDIM) {
        bias0[i] = bi0[i] + bh0[i];
        bias1[i] = bi1[i] + bh1[i];
    }
}

// ---------------- input 1x1 conv -> seq layout [t][b][2048] fp8 (x4) ----------------
__global__ __launch_bounds__(256) void k_seqprep(const float* __restrict__ x,
                                                 const float* __restrict__ w_in,
                                                 const float* __restrict__ b_in,
                                                 uchar* __restrict__ seqb) {
    int h = blockIdx.x >> 4, b = blockIdx.x & 15;
    __shared__ float xs[256][32];
    __shared__ float wl[64][257];
    int tid = threadIdx.x;
    for (int i = tid; i < 256 * 32; i += 256) {
        int c = i >> 5, w = i & 31;
        xs[c][w] = x[(((size_t)b * 256 + c) * 32 + h) * 32 + w];
    }
    for (int i = tid; i < 64 * 256; i += 256) {
        int cb = i >> 8, c = i & 255;
        wl[cb][c] = w_in[i];
    }
    __syncthreads();
    int w = (tid * 8) >> 6, cb0 = (tid * 8) & 63;
    float acc[8];
#pragma unroll
    for (int j = 0; j < 8; ++j) acc[j] = b_in[cb0 + j];
    for (int c = 0; c < 256; ++c) {
        float xv = xs[c][w];
#pragma unroll
        for (int j = 0; j < 8; ++j) acc[j] += xv * wl[cb0 + j][c];
    }
    unsigned lo = 0, hi2 = 0;
#pragma unroll
    for (int j = 0; j < 4; ++j) lo |= f2fp8(acc[j] * 4.0f) << (j * 8);
#pragma unroll
    for (int j = 0; j < 4; ++j) hi2 |= f2fp8(acc[4 + j] * 4.0f) << (j * 8);
    *(uint2*)(seqb + ((size_t)h * 16 + b) * FDIM + tid * 8) = make_uint2(lo, hi2);
}

// stage both A-operands (fp8 [b][2048]) into granule-transposed swizzled LDS.
// Cross-XCD coherent reads: relaxed agent-scope u64 atomic loads (sc-flagged, no fences).
__device__ __forceinline__ void stageA(char* At, const uchar* __restrict__ xop, const uchar* __restrict__ hop) {
    int tid = threadIdx.x;
#pragma unroll
    for (int it = 0; it < 8; ++it) {
        int u = it * 512 + tid;              // [0,4096)
        int op = u >> 11;
        int uu = u & 2047;
        int b = uu >> 7, gp2 = uu & 127;
        u64* s = (u64*)((op ? hop : xop) + b * 2048 + gp2 * 16);
        u64 lo = __hip_atomic_load(s,     __ATOMIC_RELAXED, __HIP_MEMORY_SCOPE_AGENT);
        u64 hi = __hip_atomic_load(s + 1, __ATOMIC_RELAXED, __HIP_MEMORY_SCOPE_AGENT);
        int slot = gp2 * 16 + (b ^ (gp2 & 15));
        char* d = At + (size_t)op * 32768 + (size_t)slot * 16;
        *(u64*)d = lo;
        *(u64*)(d + 8) = hi;
    }
}

// two-level grid barrier: 16 group counters (128B apart) -> root counter -> epoch line.
// All RELAXED agent atomics: no cache-wide maintenance anywhere.
__device__ __forceinline__ void gbar2(unsigned* __restrict__ cnts, unsigned* __restrict__ epoch,
                                      unsigned target, int bl) {
    __syncthreads();    // s_waitcnt vmcnt(0): all agent-scope h-stores acked at coherence point
    if (threadIdx.x == 0) {
        unsigned old = __hip_atomic_fetch_add(cnts + (size_t)(bl >> 4) * 32, 1u,
                                              __ATOMIC_RELAXED, __HIP_MEMORY_SCOPE_AGENT);
        if ((old & 15) == 15) {
            unsigned rold = __hip_atomic_fetch_add(cnts + (size_t)16 * 32, 1u,
                                                   __ATOMIC_RELAXED, __HIP_MEMORY_SCOPE_AGENT);
            if ((rold & 15) == 15)
                __hip_atomic_store(epoch, target, __ATOMIC_RELAXED, __HIP_MEMORY_SCOPE_AGENT);
        }
        while (__hip_atomic_load(epoch, __ATOMIC_RELAXED, __HIP_MEMORY_SCOPE_AGENT) < target)
            __builtin_amdgcn_s_sleep(1);
    }
    __syncthreads();
}

// one LSTM cell. Consumes wfc (preloaded weight frags); issues prefetch of wfn <- nxtw
// at entry so the next cell's 32MiB grid-wide weight stream overlaps this cell.
__device__ __forceinline__ void do_cell(char* At, float (*gbuf)[16][16],
                                        u64x2 (&wfc)[16], u64x2 (&wfn)[16],
                                        const uchar* __restrict__ nxtw,
                                        const uchar* __restrict__ xop, const uchar* __restrict__ hop,
                                        uchar* __restrict__ hdst, u16* __restrict__ odst,
                                        const float* bia, float& cst,
                                        unsigned* __restrict__ cnts, unsigned* __restrict__ epoch,
                                        unsigned target, int col, int bl) {
    int tid = threadIdx.x, lane = tid & 63, w = tid >> 6;
    int m = (w >> 1) & 1;

    {   // prefetch next cell's weight fragments (plain cached loads; static data)
        const u64x2* np = (const u64x2*)nxtw;
#pragma unroll
        for (int i = 0; i < 16; ++i) wfn[i] = np[(size_t)i * 64];
    }

    stageA(At, xop, hop);
    __syncthreads();

    f32x4 ac0 = {0.f,0.f,0.f,0.f}, ac1 = {0.f,0.f,0.f,0.f};
    f32x4 ac2 = {0.f,0.f,0.f,0.f}, ac3 = {0.f,0.f,0.f,0.f};
    const char* ab = At + m * 32768;
    int b16 = lane & 15, hi = lane >> 4;
    int loff = (hi & 1) * 8;
#pragma unroll
    for (int kk2 = 0; kk2 < 16; kk2 += 2) {
        int P0 = 4 * kk2 + (hi >> 1);
        long long a0 = *(const long long*)(ab + (P0 * 16 + (b16 ^ (P0 & 15))) * 16 + loff);
        ac0 = mfma8(a0, (long long)wfc[kk2].x, ac0);
        long long a1 = *(const long long*)(ab + ((P0 + 2) * 16 + (b16 ^ ((P0 + 2) & 15))) * 16 + loff);
        ac1 = mfma8(a1, (long long)wfc[kk2].y, ac1);
        int P2 = P0 + 4;
        long long a2 = *(const long long*)(ab + (P2 * 16 + (b16 ^ (P2 & 15))) * 16 + loff);
        ac2 = mfma8(a2, (long long)wfc[kk2 + 1].x, ac2);
        long long a3 = *(const long long*)(ab + ((P2 + 2) * 16 + (b16 ^ ((P2 + 2) & 15))) * 16 + loff);
        ac3 = mfma8(a3, (long long)wfc[kk2 + 1].y, ac3);
    }
    f32x4 acc = (ac0 + ac1) + (ac2 + ac3);
    int brow = hi * 4;
#pragma unroll
    for (int i = 0; i < 4; ++i) gbuf[w][brow + i][b16] = acc[i];
    __syncthreads();

    if (tid < 128) {
        int b = tid >> 3, f = tid & 7;
        float gv[4];
#pragma unroll
        for (int g = 0; g < 4; ++g) {
            int gpp = g >> 1, jl = ((g & 1) << 3) | f;
            float s = 0.f;
#pragma unroll
            for (int mk = 0; mk < 4; ++mk)
                s += gbuf[gpp + ((mk & 1) << 1) + ((mk >> 1) << 2)][b][jl];
            gv[g] = s * (1.0f / 128.0f) + bia[g];
        }
        float cn = sigm(gv[1]) * cst + sigm(gv[0]) * tanh_f(gv[2]);
        float hn = sigm(gv[3]) * tanh_f(cn);
        cst = cn;
        __hip_atomic_store(hdst + (size_t)b * FDIM + col, (uchar)f2fp8(hn * 4.0f),
                           __ATOMIC_RELAXED, __HIP_MEMORY_SCOPE_AGENT);
        if (odst) odst[(size_t)b * FDIM + col] = f2b(hn);
    }
    gbar2(cnts, epoch, target, bl);
}

__global__ __launch_bounds__(512, 2) void k_lstm(const uchar* __restrict__ Wp,
                                                 const float* __restrict__ bias0,
                                                 const float* __restrict__ bias1,
                                                 const uchar* __restrict__ seqb,
                                                 uchar* __restrict__ h0, uchar* __restrict__ h1,
                                                 u16* __restrict__ seqout,
                                                 unsigned* __restrict__ cnts, unsigned* __restrict__ epoch) {
    __shared__ char At[65536];
    __shared__ float gbuf[8][16][16];
    int tid = threadIdx.x, lane = tid & 63, w = tid >> 6;
    int gp = w & 1, m = (w >> 1) & 1, kh = w >> 2;
    int bl = blockIdx.x;
    size_t so0 = ((((size_t)(0 + m) * 256 + bl) * 2 + gp) * 2 + kh) * 16384 + (size_t)lane * 16;
    size_t so1 = ((((size_t)(2 + m) * 256 + bl) * 2 + gp) * 2 + kh) * 16384 + (size_t)lane * 16;
    const uchar* wp0 = Wp + so0;
    const uchar* wp1 = Wp + so1;
    int f = tid & 7, col = bl * 8 + f;
    float c0 = 0.f, c1 = 0.f;
    float bia[8];
    if (tid < 128) {
#pragma unroll
        for (int g = 0; g < 4; ++g) {
            bia[g] = bias0[g * FDIM + col];
            bia[4 + g] = bias1[g * FDIM + col];
        }
    }
    // prologue: load first cell's weight fragments
    u64x2 wfA[16], wfB[16];
    {
        const u64x2* np = (const u64x2*)wp0;
#pragma unroll
        for (int i = 0; i < 16; ++i) wfA[i] = np[(size_t)i * 64];
    }
    const size_t BF = (size_t)16 * FDIM;
    unsigned target = 0;
    for (int st = 0; st < NSTEP; ++st) {
        int cur = st & 1, prv = cur ^ 1;
        const uchar* x0 = (st < 32) ? (seqb + (size_t)st * BF) : (h1 + (size_t)prv * BF);
        target += 1;
        do_cell(At, gbuf, wfA, wfB, wp1, x0, h0 + (size_t)prv * BF,
                h0 + (size_t)cur * BF, nullptr, bia, c0, cnts, epoch, target, col, bl);
        u16* od = (st >= 31) ? (seqout + (size_t)(st - 31) * BF) : nullptr;
        target += 1;
        do_cell(At, gbuf, wfB, wfA, wp0, h0 + (size_t)cur * BF, h1 + (size_t)prv * BF,
                h1 + (size_t)cur * BF, od, bia + 4, c1, cnts, epoch, target, col, bl);
    }
}

// ---------------- copy x into top half of output ----------------
__global__ void k_copyx(const float* __restrict__ x, float* __restrict__ out) {
    size_t n = (size_t)4096 * 256;
    size_t stride = (size_t)gridDim.x * blockDim.x;
    for (size_t i = (size_t)blockIdx.x * blockDim.x + threadIdx.x; i < n; i += stride) {
        size_t bc = i >> 8, r = i & 255;
        ((float4*)out)[bc * 512 + r] = ((const float4*)x)[i];
    }
}

// ---------------- output 1x1 conv into bottom half ----------------
__global__ __launch_bounds__(256) void k_convout(const u16* __restrict__ seqout,
                                                 const float* __restrict__ w_out,
                                                 const float* __restrict__ b_out,
                                                 float* __restrict__ out) {
    int s = blockIdx.x >> 4, b = blockIdx.x & 15;
    __shared__ float srow[2048];
    int tid = threadIdx.x;
    for (int i = tid; i < 2048; i += 256) srow[i] = b2f(seqout[((size_t)s * 16 + b) * FDIM + i]);
    __syncthreads();
    int o = tid;
    float bo = b_out[o];
    float wreg[64];
#pragma unroll
    for (int cb = 0; cb < 64; ++cb) wreg[cb] = w_out[o * 64 + cb];
    for (int w4 = 0; w4 < 8; ++w4) {
        float ac0 = bo, ac1 = bo, ac2 = bo, ac3 = bo;
#pragma unroll
        for (int cb = 0; cb < 64; ++cb) {
            float wv = wreg[cb];
            ac0 += srow[(w4 * 4 + 0) * 64 + cb] * wv;
            ac1 += srow[(w4 * 4 + 1) * 64 + cb] * wv;
            ac2 += srow[(w4 * 4 + 2) * 64 + cb] * wv;
            ac3 += srow[(w4 * 4 + 3) * 64 + cb] * wv;
        }
        float4 v; v.x = ac0; v.y = ac1; v.z = ac2; v.w = ac3;
        *(float4*)&out[(((size_t)b * 256 + o) * 64 + 32 + s) * 32 + w4 * 4] = v;
    }
}

extern "C" void kernel_launch(void* const* d_in, const int* in_sizes, int n_in,
                              void* d_out, int out_size, void* d_ws, size_t ws_size,
                              hipStream_t stream) {
    const float* x    = (const float*)d_in[0];
    const float* w_in = (const float*)d_in[1];
    const float* b_in = (const float*)d_in[2];
    const float* Wih0 = (const float*)d_in[3];
    const float* Whh0 = (const float*)d_in[4];
    const float* bih0 = (const float*)d_in[5];
    const float* bhh0 = (const float*)d_in[6];
    const float* Wih1 = (const float*)d_in[7];
    const float* Whh1 = (const float*)d_in[8];
    const float* bih1 = (const float*)d_in[9];
    const float* bhh1 = (const float*)d_in[10];
    const float* wout = (const float*)d_in[11];
    const float* bout = (const float*)d_in[12];
    float* out = (float*)d_out;
    char* ws = (char*)d_ws;

    uchar* Wp = (uchar*)ws;
    size_t off = (size_t)64 * 1024 * 1024;               // fp8 packed weights
    float* bias0 = (float*)(ws + off); off += 4 * FDIM * 4;
    float* bias1 = (float*)(ws + off); off += 4 * FDIM * 4;
    uchar* seqb = (uchar*)(ws + off); off += (size_t)32 * 16 * FDIM;
    u16* seqout = (u16*)(ws + off); off += (size_t)32 * 16 * FDIM * 2;
    size_t zoff = off;
    uchar* h0 = (uchar*)(ws + off); off += (size_t)2 * 16 * FDIM;
    uchar* h1 = (uchar*)(ws + off); off += (size_t)2 * 16 * FDIM;
    off = (off + 127) & ~(size_t)127;
    unsigned* cnts = (unsigned*)(ws + off); off += 17 * 32 * 4;   // 16 group lines + root line
    off = (off + 127) & ~(size_t)127;
    unsigned* epoch = (unsigned*)(ws + off); off += 128;

    hipMemsetAsync(ws + zoff, 0, off - zoff, stream);

    k_pack<<<8192, 256, 0, stream>>>(Wih0, Whh0, Wih1, Whh1, Wp);
    k_bias<<<32, 256, 0, stream>>>(bih0, bhh0, bih1, bhh1, bias0, bias1);
    k_seqprep<<<512, 256, 0, stream>>>(x, w_in, b_in, seqb);
    k_lstm<<<NBLK, 512, 0, stream>>>(Wp, bias0, bias1, seqb, h0, h1, seqout, cnts, epoch);
    k_copyx<<<2048, 256, 0, stream>>>(x, out);
    k_convout<<<512, 256, 0, stream>>>(seqout, wout, bout, out);
}